// Round 5
// baseline (1186.122 us; speedup 1.0000x reference)
//
#include <hip/hip_runtime.h>
#include <hip/hip_cooperative_groups.h>
#include <math.h>

namespace cg = cooperative_groups;

typedef unsigned short u16;
typedef unsigned int u32;
using bf16x8 = __attribute__((ext_vector_type(8))) short;
using f32x4  = __attribute__((ext_vector_type(4))) float;

#define DD 4096
#define NB 256            // batch
#define SPLIT_K 4
#define PSTRIDE (NB * DD) // elements per partial buffer
#define PLANE (NB * DD)   // floats per transform layer plane

__device__ __forceinline__ u16 f2bf(float f) {
  unsigned int u = __float_as_uint(f);
  u += 0x7fffu + ((u >> 16) & 1u);   // RNE
  return (u16)(u >> 16);
}
__device__ __forceinline__ float bf2f(u16 h) {
  return __uint_as_float((u32)h << 16);
}
__device__ __forceinline__ unsigned int pack2bf(float a, float b) {
  return (unsigned int)f2bf(a) | ((unsigned int)f2bf(b) << 16);
}
__device__ __forceinline__ void async_cp16(const u16* g, u16* l) {
  __builtin_amdgcn_global_load_lds(
      (const __attribute__((address_space(1))) unsigned int*)g,
      (__attribute__((address_space(3))) unsigned int*)l, 16, 0, 0);
}

// --------------------------- shared-memory unions ---------------------------
struct GemmSmem {                    // 112 KB
  u16 As[3][256 * 64];
  u16 Bs[2][64 * 64];
};
struct UpdSmem {                     // ~48 KB
  float dY[64][68];
  float U[64][17], V[64][17], P[64][17], Q[64][17], F[64][17];
  float S[16][16], dSs[16][17], T1[16][17], G1[16][17], G2[16][17], M1[16][17];
  float sinv[16];
  float RS[512];
};
struct PackSmem { float buf[512 * 9]; };
struct ClsSmem  { float red[8][10]; };

// ------------------------------- GEMM phase ---------------------------------
// part[kz] = Xf(bf16) @ W^T over K-chunk kz, output bf16. WG g: nt=g&63,
// kz=g>>6. Tile 256x64, BK=64, 2-deep prefetch, counted vmcnt.
__device__ __forceinline__ void gemm_phase(
    GemmSmem& sm, const u16* __restrict__ A, const float* __restrict__ W,
    u16* __restrict__ part, int g, int t)
{
  const int nt = g & 63, kz = g >> 6;
  const int w = t >> 6, l = t & 63;
  const int colg0 = nt << 6;
  const int k0 = kz << 10;

  f32x4 acc[4][2];
#pragma unroll
  for (int mi = 0; mi < 4; ++mi)
#pragma unroll
    for (int nj = 0; nj < 2; ++nj)
      acc[mi][nj] = (f32x4){0.f, 0.f, 0.f, 0.f};

  const int wm = w & 3, wn = w >> 2;
  const int lr = l & 15, lg = l >> 4;
  const int arow_l = (w << 3) + (l >> 3);
  const int acl = l & 7;
  const int bn_l = t >> 3;
  const int bcc = t & 7;

  float4 bs0[3], bs1[3];

#define ISSUE_A(tt, buf) do {                                                \
    const int kkk = k0 + ((tt) << 6);                                        \
    _Pragma("unroll")                                                        \
    for (int r = 0; r < 4; ++r) {                                            \
      const int row = (r << 6) + arow_l;                                     \
      const int cs = acl ^ (row & 7);                                        \
      async_cp16(A + ((size_t)row << 12) + kkk + (cs << 3),                  \
                 &sm.As[buf][(r << 12) + (w << 9)]);                         \
    } } while (0)

#define LOAD_B(tt, set) do {                                                 \
    const float* wsrc = W + ((size_t)(colg0 + bn_l) << 12) + k0 +            \
                        ((tt) << 6) + (bcc << 3);                            \
    bs0[set] = *reinterpret_cast<const float4*>(wsrc);                       \
    bs1[set] = *reinterpret_cast<const float4*>(wsrc + 4);                   \
  } while (0)

  ISSUE_A(0, 0); LOAD_B(0, 0);
  ISSUE_A(1, 1); LOAD_B(1, 1);

#pragma unroll
  for (int tt = 0; tt < 16; ++tt) {
    const int cb = tt % 3, nb = (tt + 2) % 3, pb = tt & 1;
    if (tt + 2 < 16) { ISSUE_A(tt + 2, nb); LOAD_B(tt + 2, nb); }
    if (tt < 14)       { asm volatile("s_waitcnt vmcnt(12)" ::: "memory"); }
    else if (tt == 14) { asm volatile("s_waitcnt vmcnt(6)"  ::: "memory"); }
    else               { asm volatile("s_waitcnt vmcnt(0)"  ::: "memory"); }
    __builtin_amdgcn_sched_barrier(0);
    {
      uint4 pk;
      pk.x = pack2bf(bs0[cb].x, bs0[cb].y);
      pk.y = pack2bf(bs0[cb].z, bs0[cb].w);
      pk.z = pack2bf(bs1[cb].x, bs1[cb].y);
      pk.w = pack2bf(bs1[cb].z, bs1[cb].w);
      *reinterpret_cast<uint4*>(&sm.Bs[pb][(bn_l << 6) + ((bcc ^ (bn_l & 7)) << 3)]) = pk;
    }
    asm volatile("s_waitcnt lgkmcnt(0)" ::: "memory");
    __builtin_amdgcn_s_barrier();
    __builtin_amdgcn_sched_barrier(0);
#pragma unroll
    for (int ks = 0; ks < 2; ++ks) {
      const int cg2 = (ks << 2) + lg;
      bf16x8 av[4], bv[2];
#pragma unroll
      for (int mi = 0; mi < 4; ++mi) {
        const int fr = (wm << 6) + (mi << 4) + lr;
        av[mi] = *reinterpret_cast<const bf16x8*>(&sm.As[cb][(fr << 6) + ((cg2 ^ (fr & 7)) << 3)]);
      }
#pragma unroll
      for (int nj = 0; nj < 2; ++nj) {
        const int fc = (wn << 5) + (nj << 4) + lr;
        bv[nj] = *reinterpret_cast<const bf16x8*>(&sm.Bs[pb][(fc << 6) + ((cg2 ^ (fc & 7)) << 3)]);
      }
#pragma unroll
      for (int mi = 0; mi < 4; ++mi)
#pragma unroll
        for (int nj = 0; nj < 2; ++nj)
          acc[mi][nj] = __builtin_amdgcn_mfma_f32_16x16x32_bf16(
              av[mi], bv[nj], acc[mi][nj], 0, 0, 0);
    }
    __builtin_amdgcn_s_barrier();
  }
#undef ISSUE_A
#undef LOAD_B

  u16* pout = part + (size_t)kz * PSTRIDE;
#pragma unroll
  for (int mi = 0; mi < 4; ++mi)
#pragma unroll
    for (int nj = 0; nj < 2; ++nj) {
      const int col = colg0 + (wn << 5) + (nj << 4) + lr;
#pragma unroll
      for (int j = 0; j < 4; ++j) {
        const int row = (wm << 6) + (mi << 4) + (lg << 2) + j;
        pout[((size_t)row << 12) + col] = f2bf(acc[mi][nj][j]);
      }
    }
}

// ------------------------- Stiefel update (512 thr) --------------------------
// new_A = A - H^2 * F @ (A^T F) @ (A^T A)   (Cayley collapsed; H^4 ~ 1e-13)
__device__ __forceinline__ void stiefel_update512(
    UpdSmem& m, float (&Am)[64][17], float (&Dm)[64][17],
    int t, float* __restrict__ gout, size_t ub)
{
  const int p = t >> 3;
  const int j0 = (t << 1) & 15;
  {
    const int half = t & 1, i = t >> 5, j = (t >> 1) & 15;
    float a = 0.f;
    const int r0 = half << 5;
    for (int r = r0; r < r0 + 32; ++r) a += Am[r][i] * Dm[r][j];
    m.RS[t] = a;
  }
  __syncthreads();
  if (t < 256) m.T1[t >> 4][t & 15] = m.RS[t << 1] + m.RS[(t << 1) + 1];
  __syncthreads();
  {
    float f0 = Dm[p][j0], f1 = Dm[p][j0 + 1];
    for (int k = 0; k < 16; ++k) {
      const float ak = Am[p][k];
      f0 -= ak * m.T1[k][j0];
      f1 -= ak * m.T1[k][j0 + 1];
    }
    m.F[p][j0] = f0; m.F[p][j0 + 1] = f1;
  }
  __syncthreads();
  if (t < 256) {
    const int i = t >> 4, j = t & 15;
    float g = 0.f;
    for (int r = 0; r < 64; ++r) g += Am[r][i] * m.F[r][j];
    m.G1[i][j] = g;
  } else {
    const int tt = t - 256, i = tt >> 4, j = tt & 15;
    float g = 0.f;
    for (int r = 0; r < 64; ++r) g += Am[r][i] * Am[r][j];
    m.G2[i][j] = g;
  }
  __syncthreads();
  if (t < 256) {
    const int i = t >> 4, j = t & 15;
    float mm = 0.f;
    for (int k = 0; k < 16; ++k) mm += m.G1[i][k] * m.G2[k][j];
    m.M1[i][j] = mm;
  }
  __syncthreads();
  {
    float a0 = 0.f, a1 = 0.f;
    for (int k = 0; k < 16; ++k) {
      const float fk = m.F[p][k];
      a0 += fk * m.M1[k][j0];
      a1 += fk * m.M1[k][j0 + 1];
    }
    const float n0 = Am[p][j0] - 1e-6f * a0;
    const float n1 = Am[p][j0 + 1] - 1e-6f * a1;
    __syncthreads();
    Am[p][j0] = n0; Am[p][j0 + 1] = n1;
    *reinterpret_cast<float2*>(gout + ub + (p << 4) + j0) = make_float2(n0, n1);
  }
  __syncthreads();
}

// Xf = (U @ S) @ V^T ; writes f32 Xf, bf16 Xfb, optional layer plane.
__device__ __forceinline__ void write_xf_tail(
    UpdSmem& m, int t, int b, float* __restrict__ Xf, u16* __restrict__ Xfb,
    float* __restrict__ outL_plane)
{
  const int p = t >> 3;
  const int j0 = (t << 1) & 15;
  {
    float a0 = 0.f, a1 = 0.f;
    for (int k = 0; k < 16; ++k) {
      const float uk = m.U[p][k];
      a0 += uk * m.S[k][j0];
      a1 += uk * m.S[k][j0 + 1];
    }
    m.P[p][j0] = a0; m.P[p][j0 + 1] = a1;
  }
  __syncthreads();
  {
    const int q0 = (t & 7) << 3;
    float res[8];
#pragma unroll
    for (int e = 0; e < 8; ++e) res[e] = 0.f;
    for (int i = 0; i < 16; ++i) {
      const float pi = m.P[p][i];
#pragma unroll
      for (int e = 0; e < 8; ++e) res[e] += pi * m.V[q0 + e][i];
    }
    const size_t ko = ((size_t)b << 12) + (p << 6) + q0;
    float4* xo = reinterpret_cast<float4*>(Xf + ko);
    const float4 r0 = make_float4(res[0], res[1], res[2], res[3]);
    const float4 r1 = make_float4(res[4], res[5], res[6], res[7]);
    xo[0] = r0; xo[1] = r1;
    uint4 pk;
    pk.x = pack2bf(res[0], res[1]); pk.y = pack2bf(res[2], res[3]);
    pk.z = pack2bf(res[4], res[5]); pk.w = pack2bf(res[6], res[7]);
    *reinterpret_cast<uint4*>(Xfb + ko) = pk;
    if (outL_plane != nullptr) {
      float4* op = reinterpret_cast<float4*>(outL_plane + ko);
      op[0] = r0; op[1] = r1;
    }
  }
}

// ------------------------------ update phase --------------------------------
__device__ __forceinline__ void update_phase(
    UpdSmem& m, const u16* __restrict__ part, const float* __restrict__ bias,
    float* __restrict__ u_g, float* __restrict__ v_g, float* __restrict__ s_g,
    float* __restrict__ Xf, u16* __restrict__ Xfb,
    float* __restrict__ outL_plane, int b, int t)
{
  const size_t ub = (size_t)b << 10;
  {
    const float2 u2 = *reinterpret_cast<const float2*>(u_g + ub + (t << 1));
    const float2 v2 = *reinterpret_cast<const float2*>(v_g + ub + (t << 1));
    const int r = t >> 3, c = (t & 7) << 1;
    m.U[r][c] = u2.x; m.U[r][c + 1] = u2.y;
    m.V[r][c] = v2.x; m.V[r][c + 1] = v2.y;
    if (t < 256) m.S[t >> 4][t & 15] = s_g[((size_t)b << 8) + t];
  }
  __syncthreads();
  if (t < 16) m.sinv[t] = 1.0f / m.S[t][t];
  {
    const u16* p0 = part + ((size_t)b << 12) + (t << 3);
    float x[8];
#pragma unroll
    for (int e = 0; e < 8; ++e) x[e] = 0.f;
#pragma unroll
    for (int kzi = 0; kzi < 4; ++kzi) {
      const uint4 v = *reinterpret_cast<const uint4*>(p0 + (size_t)kzi * PSTRIDE);
      x[0] += bf2f((u16)(v.x & 0xffff)); x[1] += bf2f((u16)(v.x >> 16));
      x[2] += bf2f((u16)(v.y & 0xffff)); x[3] += bf2f((u16)(v.y >> 16));
      x[4] += bf2f((u16)(v.z & 0xffff)); x[5] += bf2f((u16)(v.z >> 16));
      x[6] += bf2f((u16)(v.w & 0xffff)); x[7] += bf2f((u16)(v.w >> 16));
    }
    if (bias != nullptr) {
      const float4 b0 = *reinterpret_cast<const float4*>(bias + (t << 3));
      const float4 b1 = *reinterpret_cast<const float4*>(bias + (t << 3) + 4);
      x[0] += b0.x; x[1] += b0.y; x[2] += b0.z; x[3] += b0.w;
      x[4] += b1.x; x[5] += b1.y; x[6] += b1.z; x[7] += b1.w;
    }
    const int r = t >> 3, c = (t & 7) << 3;
    float4* d0 = reinterpret_cast<float4*>(&m.dY[r][c]);
    d0[0] = make_float4(fmaxf(x[0], 0.f), fmaxf(x[1], 0.f), fmaxf(x[2], 0.f), fmaxf(x[3], 0.f));
    d0[1] = make_float4(fmaxf(x[4], 0.f), fmaxf(x[5], 0.f), fmaxf(x[6], 0.f), fmaxf(x[7], 0.f));
  }
  __syncthreads();
  const int p = t >> 3;
  const int j0 = (t << 1) & 15;
  {
    float a0 = 0.f, a1 = 0.f;
    for (int q = 0; q < 64; ++q) {
      const float d = m.dY[p][q];
      a0 += d * m.V[q][j0];
      a1 += d * m.V[q][j0 + 1];
    }
    m.P[p][j0] = a0; m.P[p][j0 + 1] = a1;
    float b0 = 0.f, b1 = 0.f;
    for (int r = 0; r < 64; ++r) {
      const float d = m.dY[r][p];
      b0 += d * m.U[r][j0];
      b1 += d * m.U[r][j0 + 1];
    }
    m.Q[p][j0] = b0; m.Q[p][j0 + 1] = b1;
  }
  __syncthreads();
  {
    const int half = t & 1, i = t >> 5, j = (t >> 1) & 15;
    float a = 0.f;
    const int r0 = half << 5;
    for (int r = r0; r < r0 + 32; ++r) a += m.U[r][i] * m.P[r][j];
    m.RS[t] = a;
  }
  __syncthreads();
  if (t < 256) m.dSs[t >> 4][t & 15] = m.RS[t << 1] + m.RS[(t << 1) + 1];
  __syncthreads();
  for (int i = t; i < 1024; i += 512) {
    const int r = i >> 4, c = i & 15;
    const float sc = m.sinv[c];
    m.P[r][c] *= sc;
    m.Q[r][c] *= sc;
  }
  __syncthreads();

  stiefel_update512(m, m.U, m.P, t, u_g, ub);
  stiefel_update512(m, m.V, m.Q, t, v_g, ub);

  if (t < 256) {
    const int i = t >> 4, j = t & 15;
    const float ns = m.S[i][j] + 1e-3f * m.dSs[i][j];
    m.S[i][j] = ns;
    s_g[((size_t)b << 8) + t] = ns;
  }
  __syncthreads();
  write_xf_tail(m, t, b, Xf, Xfb, outL_plane);
}

// ------------------------------- init phase ---------------------------------
__device__ __forceinline__ void init_phase(
    UpdSmem& m, const float* __restrict__ X,
    float* __restrict__ u_g, float* __restrict__ v_g, float* __restrict__ s_g,
    float* __restrict__ Xf, u16* __restrict__ Xfb, int b, int t)
{
  const float* xb = X + (size_t)b * 3072;
  const size_t ub = (size_t)b << 10;
  {
    const float2 u2 = *reinterpret_cast<const float2*>(xb + (t << 1));
    const int r = t >> 3, c = (t & 7) << 1;
    m.U[r][c] = u2.x; m.U[r][c + 1] = u2.y;
    *reinterpret_cast<float2*>(u_g + ub + (t << 1)) = u2;
    if (t < 256) {
      const float sv = xb[1024 + t];
      m.S[t >> 4][t & 15] = sv;
      s_g[((size_t)b << 8) + t] = sv;
    }
    // vh (16,64) -> v (64,16); 2 consecutive elements of row iv
    const float2 v2 = *reinterpret_cast<const float2*>(xb + 2048 + (t << 1));
    const int g2 = t << 1;
    const int iv = g2 >> 6, q = g2 & 63;
    m.V[q][iv] = v2.x; m.V[q + 1][iv] = v2.y;
    v_g[ub + (size_t)q * 16 + iv] = v2.x;
    v_g[ub + (size_t)(q + 1) * 16 + iv] = v2.y;
  }
  __syncthreads();
  write_xf_tail(m, t, b, Xf, Xfb, nullptr);
}

// ------------------------------- mega kernel --------------------------------
__global__ __launch_bounds__(512, 2) void mega_kernel(
    const float* __restrict__ X, const float* __restrict__ W0,
    const float* __restrict__ W, const float* __restrict__ bb,
    const float* __restrict__ Wc, const float* __restrict__ bc,
    float* __restrict__ pred, float* __restrict__ cls, float* __restrict__ outT,
    float* __restrict__ Xf, u16* __restrict__ part,
    float* __restrict__ u_g, float* __restrict__ v_g, float* __restrict__ s_g,
    u16* __restrict__ Xfb, float* __restrict__ outL)
{
  cg::grid_group grid = cg::this_grid();
  __shared__ __align__(16) char smem_raw[sizeof(GemmSmem)];
  GemmSmem& gs = *reinterpret_cast<GemmSmem*>(smem_raw);
  UpdSmem&  us = *reinterpret_cast<UpdSmem*>(smem_raw);
  PackSmem& ps = *reinterpret_cast<PackSmem*>(smem_raw);
  ClsSmem&  cs = *reinterpret_cast<ClsSmem*>(smem_raw);

  const int g = blockIdx.x, t = threadIdx.x;

  init_phase(us, X, u_g, v_g, s_g, Xf, Xfb, g, t);
  grid.sync();

  for (int layer = 0; layer <= 8; ++layer) {
    const float* Wl = (layer == 0) ? W0 : W + (size_t)(layer - 1) * DD * DD;
    gemm_phase(gs, Xfb, Wl, part, g, t);
    grid.sync();
    update_phase(us, part, (layer == 0) ? nullptr : (bb + (size_t)(layer - 1) * DD),
                 u_g, v_g, s_g, Xf, Xfb,
                 outL + (size_t)layer * PLANE, g, t);
    grid.sync();
  }

  // ---- classifier: sample g ----
  {
    const int lane = t & 63, w = t >> 6;
    float acc[10];
#pragma unroll
    for (int c = 0; c < 10; ++c) acc[c] = 0.f;
    const float* xr = Xf + ((size_t)g << 12);
    for (int k = t; k < 4096; k += 512) {
      const float x = xr[k];
#pragma unroll
      for (int c = 0; c < 10; ++c) acc[c] += x * Wc[c * 4096 + k];
    }
#pragma unroll
    for (int c = 0; c < 10; ++c)
      for (int off = 32; off; off >>= 1) acc[c] += __shfl_xor(acc[c], off);
    if (lane == 0)
#pragma unroll
      for (int c = 0; c < 10; ++c) cs.red[w][c] = acc[c];
    __syncthreads();
    if (t == 0) {
      float lg[10], ex[10];
      float mx = -1e30f;
#pragma unroll
      for (int c = 0; c < 10; ++c) {
        float s8 = 0.f;
#pragma unroll
        for (int ww = 0; ww < 8; ++ww) s8 += cs.red[ww][c];
        lg[c] = s8 + bc[c];
        mx = fmaxf(mx, lg[c]);
      }
      float s = 0.f;
#pragma unroll
      for (int c = 0; c < 10; ++c) { ex[c] = expf(lg[c] - mx); s += ex[c]; }
      const float inv = 1.f / s;
#pragma unroll
      for (int c = 0; c < 10; ++c) {
        cls[g * 10 + c] = lg[c];
        pred[g * 10 + c] = ex[c] * inv;
      }
    }
    __syncthreads();
  }

  // ---- pack: outT[b,k,9] <- outL[9][b,k]; WG g covers 8 chunks of 512 ----
  for (int it = 0; it < 8; ++it) {
    const int base = ((g << 3) + it) << 9;
#pragma unroll
    for (int l = 0; l < 9; ++l)
      ps.buf[t * 9 + l] = outL[(size_t)l * PLANE + base + t];
    __syncthreads();
    const float4* b4 = reinterpret_cast<const float4*>(ps.buf);
    float4* o4 = reinterpret_cast<float4*>(outT + (size_t)base * 9);
    for (int i = t; i < 1152; i += 512) o4[i] = b4[i];
    __syncthreads();
  }
}

extern "C" void kernel_launch(void* const* d_in, const int* in_sizes, int n_in,
                              void* d_out, int out_size, void* d_ws, size_t ws_size,
                              hipStream_t stream) {
  (void)in_sizes; (void)n_in; (void)out_size; (void)ws_size;
  const float* X  = (const float*)d_in[0];
  const float* W0 = (const float*)d_in[1];
  const float* W  = (const float*)d_in[2];
  const float* bb = (const float*)d_in[3];
  const float* Wc = (const float*)d_in[4];
  const float* bc = (const float*)d_in[5];

  float* out_pred  = (float*)d_out;
  float* out_cls   = out_pred + 2560;
  float* out_trans = out_pred + 5120;

  char* ws = (char*)d_ws;
  float* Xf   = (float*)(ws);                      // 4 MB
  u16*   part = (u16*)  (ws + (4ull << 20));       // 8 MB (4 bf16 split-K partials)
  float* u_g  = (float*)(ws + (20ull << 20));      // 1 MB
  float* v_g  = (float*)(ws + (21ull << 20));      // 1 MB
  float* s_g  = (float*)(ws + (22ull << 20));      // 256 KB
  u16*   Xfb  = (u16*)  (ws + (23ull << 20));      // 2 MB
  float* outL = (float*)(ws + (25ull << 20));      // 36 MB (9 layer planes)

  void* kargs[] = {
    (void*)&X, (void*)&W0, (void*)&W, (void*)&bb, (void*)&Wc, (void*)&bc,
    (void*)&out_pred, (void*)&out_cls, (void*)&out_trans,
    (void*)&Xf, (void*)&part, (void*)&u_g, (void*)&v_g, (void*)&s_g,
    (void*)&Xfb, (void*)&outL
  };
  hipLaunchCooperativeKernel((const void*)mega_kernel, dim3(256), dim3(512),
                             kargs, 0, stream);
}

// Round 6
// 439.064 us; speedup vs baseline: 2.7015x; 2.7015x over previous
//
#include <hip/hip_runtime.h>
#include <math.h>

typedef unsigned short u16;
typedef unsigned int u32;
using bf16x8 = __attribute__((ext_vector_type(8))) short;
using f32x4  = __attribute__((ext_vector_type(4))) float;

#define DD 4096
#define NB 256            // batch
#define SPLIT_K 8
#define PSTRIDE (NB * DD) // elements per partial plane
#define PLANE (NB * DD)   // floats per transform layer plane

__device__ __forceinline__ u16 f2bf(float f) {
  unsigned int u = __float_as_uint(f);
  u += 0x7fffu + ((u >> 16) & 1u);   // RNE
  return (u16)(u >> 16);
}
__device__ __forceinline__ float bf2f(u16 h) {
  return __uint_as_float((u32)h << 16);
}
__device__ __forceinline__ unsigned int pack2bf(float a, float b) {
  return (unsigned int)f2bf(a) | ((unsigned int)f2bf(b) << 16);
}
__device__ __forceinline__ void async_cp16(const u16* g, u16* l) {
  __builtin_amdgcn_global_load_lds(
      (const __attribute__((address_space(1))) unsigned int*)g,
      (__attribute__((address_space(3))) unsigned int*)l, 16, 0, 0);
}

// ---------------------------------------------------------------------------
// GEMM: part[kz] = Xf(bf16) @ W^T over K-chunk kz (K=512), output bf16.
// grid (64 n-tiles, 8 k-splits) = 512 WGs = 2 WGs/CU (40 KB LDS, <=128 VGPR).
// Single-buffered simple loop: inter-WG overlap hides per-iter drain.
// ---------------------------------------------------------------------------
__global__ __launch_bounds__(512, 4) void gemm_kernel(
    const u16* __restrict__ A, const float* __restrict__ W,
    u16* __restrict__ part)
{
  const int nt = blockIdx.x;
  const int kz = blockIdx.y;
  const int t = threadIdx.x;
  const int w = t >> 6, l = t & 63;

  __shared__ __align__(16) u16 As[256 * 64];   // 32 KB
  __shared__ __align__(16) u16 Bs[64 * 64];    // 8 KB

  const int colg0 = nt << 6;
  const int k0 = kz << 9;                      // K-chunk of 512

  f32x4 acc[4][2];
#pragma unroll
  for (int mi = 0; mi < 4; ++mi)
#pragma unroll
    for (int nj = 0; nj < 2; ++nj)
      acc[mi][nj] = (f32x4){0.f, 0.f, 0.f, 0.f};

  const int wm = w & 3, wn = w >> 2;      // wave tile: rows 64*wm, cols 32*wn
  const int lr = l & 15, lg = l >> 4;
  const int arow_l = (w << 3) + (l >> 3); // A stage row (per rep +64)
  const int acl = l & 7;                  // linear chunk within row
  const int bn_l = t >> 3;                // B stage: W row (output col)
  const int bcc = t & 7;                  // B stage: chunk

  for (int tt = 0; tt < 8; ++tt) {
    const int kk = k0 + (tt << 6);
    __syncthreads();                      // LDS safe to overwrite
    // stage A: 256x64 bf16, linear LDS dest, source chunk pre-swizzled
#pragma unroll
    for (int r = 0; r < 4; ++r) {
      const int row = (r << 6) + arow_l;
      const int cs = acl ^ (row & 7);
      async_cp16(A + ((size_t)row << 12) + kk + (cs << 3),
                 &As[(r << 12) + (w << 9)]);
    }
    // stage B: 64(out col) x 64(k) fp32 -> bf16, swizzled ds_write
    {
      const float* wsrc = W + ((size_t)(colg0 + bn_l) << 12) + kk + (bcc << 3);
      const float4 f0 = *reinterpret_cast<const float4*>(wsrc);
      const float4 f1 = *reinterpret_cast<const float4*>(wsrc + 4);
      uint4 pk;
      pk.x = pack2bf(f0.x, f0.y);
      pk.y = pack2bf(f0.z, f0.w);
      pk.z = pack2bf(f1.x, f1.y);
      pk.w = pack2bf(f1.z, f1.w);
      *reinterpret_cast<uint4*>(&Bs[(bn_l << 6) + ((bcc ^ (bn_l & 7)) << 3)]) = pk;
    }
    __syncthreads();                      // vmcnt(0)+lgkmcnt(0)+barrier
#pragma unroll
    for (int ks = 0; ks < 2; ++ks) {
      const int cg = (ks << 2) + lg;
      bf16x8 av[4], bv[2];
#pragma unroll
      for (int mi = 0; mi < 4; ++mi) {
        const int fr = (wm << 6) + (mi << 4) + lr;
        av[mi] = *reinterpret_cast<const bf16x8*>(&As[(fr << 6) + ((cg ^ (fr & 7)) << 3)]);
      }
#pragma unroll
      for (int nj = 0; nj < 2; ++nj) {
        const int fc = (wn << 5) + (nj << 4) + lr;
        bv[nj] = *reinterpret_cast<const bf16x8*>(&Bs[(fc << 6) + ((cg ^ (fc & 7)) << 3)]);
      }
#pragma unroll
      for (int mi = 0; mi < 4; ++mi)
#pragma unroll
        for (int nj = 0; nj < 2; ++nj)
          acc[mi][nj] = __builtin_amdgcn_mfma_f32_16x16x32_bf16(
              av[mi], bv[nj], acc[mi][nj], 0, 0, 0);
    }
  }

  u16* pout = part + (size_t)kz * PSTRIDE;
#pragma unroll
  for (int mi = 0; mi < 4; ++mi)
#pragma unroll
    for (int nj = 0; nj < 2; ++nj) {
      const int col = colg0 + (wn << 5) + (nj << 4) + lr;
#pragma unroll
      for (int j = 0; j < 4; ++j) {
        const int row = (wm << 6) + (mi << 4) + (lg << 2) + j;
        pout[((size_t)row << 12) + col] = f2bf(acc[mi][nj][j]);
      }
    }
}

// ---------------------------------------------------------------------------
// Per-sample fused update, 512 threads. Cayley collapsed analytically:
//   new_A = A - H^2 * F @ (A^T F) @ (A^T A)   (exact to fp32; H^4 ~ 1e-13)
// ---------------------------------------------------------------------------
__device__ __forceinline__ void stiefel_update512(
    float (&Am)[64][17], float (&Dm)[64][17], float (&Fm)[64][17],
    float (&T1)[16][17], float (&G1)[16][17], float (&G2)[16][17],
    float (&M1)[16][17], float (&RS)[512],
    int t, float* __restrict__ gout, size_t ub)
{
  const int p = t >> 3;              // 0..63
  const int j0 = (t << 1) & 15;      // even col
  {
    const int half = t & 1, i = t >> 5, j = (t >> 1) & 15;
    float a = 0.f;
    const int r0 = half << 5;
    for (int r = r0; r < r0 + 32; ++r) a += Am[r][i] * Dm[r][j];
    RS[t] = a;
  }
  __syncthreads();
  if (t < 256) T1[t >> 4][t & 15] = RS[t << 1] + RS[(t << 1) + 1];
  __syncthreads();
  {
    float f0 = Dm[p][j0], f1 = Dm[p][j0 + 1];
    for (int k = 0; k < 16; ++k) {
      const float ak = Am[p][k];
      f0 -= ak * T1[k][j0];
      f1 -= ak * T1[k][j0 + 1];
    }
    Fm[p][j0] = f0; Fm[p][j0 + 1] = f1;
  }
  __syncthreads();
  if (t < 256) {
    const int i = t >> 4, j = t & 15;
    float g = 0.f;
    for (int r = 0; r < 64; ++r) g += Am[r][i] * Fm[r][j];
    G1[i][j] = g;
  } else {
    const int tt = t - 256, i = tt >> 4, j = tt & 15;
    float g = 0.f;
    for (int r = 0; r < 64; ++r) g += Am[r][i] * Am[r][j];
    G2[i][j] = g;
  }
  __syncthreads();
  if (t < 256) {
    const int i = t >> 4, j = t & 15;
    float m = 0.f;
    for (int k = 0; k < 16; ++k) m += G1[i][k] * G2[k][j];
    M1[i][j] = m;
  }
  __syncthreads();
  {
    float a0 = 0.f, a1 = 0.f;
    for (int k = 0; k < 16; ++k) {
      const float fk = Fm[p][k];
      a0 += fk * M1[k][j0];
      a1 += fk * M1[k][j0 + 1];
    }
    const float n0 = Am[p][j0] - 1e-6f * a0;
    const float n1 = Am[p][j0 + 1] - 1e-6f * a1;
    __syncthreads();
    Am[p][j0] = n0; Am[p][j0 + 1] = n1;
    *reinterpret_cast<float2*>(gout + ub + (p << 4) + j0) = make_float2(n0, n1);
  }
  __syncthreads();
}

__global__ __launch_bounds__(512) void update_kernel(
    const u16* __restrict__ part, const float* __restrict__ bias,
    float* __restrict__ u_g, float* __restrict__ v_g, float* __restrict__ s_g,
    float* __restrict__ Xf, u16* __restrict__ Xfb,
    float* __restrict__ outL, int layer)
{
  const int b = blockIdx.x, t = threadIdx.x;
  __shared__ float dY[64][68];
  __shared__ float U[64][17], V[64][17];
  __shared__ float P[64][17], Q[64][17], F[64][17];
  __shared__ float S[16][16], dSs[16][17], T1[16][17], G1[16][17], G2[16][17], M1[16][17];
  __shared__ float sinv[16];
  __shared__ float RS[512];

  const size_t ub = (size_t)b << 10;
  {
    const float2 u2 = *reinterpret_cast<const float2*>(u_g + ub + (t << 1));
    const float2 v2 = *reinterpret_cast<const float2*>(v_g + ub + (t << 1));
    const int r = t >> 3, c = (t & 7) << 1;
    U[r][c] = u2.x; U[r][c + 1] = u2.y;
    V[r][c] = v2.x; V[r][c + 1] = v2.y;
    if (t < 256) S[t >> 4][t & 15] = s_g[((size_t)b << 8) + t];
  }
  __syncthreads();
  if (t < 16) sinv[t] = 1.0f / S[t][t];
  // dY = relu(sum of 8 bf16 partials + bias); 8 elems per thread
  {
    const u16* p0 = part + ((size_t)b << 12) + (t << 3);
    float x[8];
#pragma unroll
    for (int e = 0; e < 8; ++e) x[e] = 0.f;
#pragma unroll
    for (int kzi = 0; kzi < SPLIT_K; ++kzi) {
      const uint4 v = *reinterpret_cast<const uint4*>(p0 + (size_t)kzi * PSTRIDE);
      x[0] += bf2f((u16)(v.x & 0xffff)); x[1] += bf2f((u16)(v.x >> 16));
      x[2] += bf2f((u16)(v.y & 0xffff)); x[3] += bf2f((u16)(v.y >> 16));
      x[4] += bf2f((u16)(v.z & 0xffff)); x[5] += bf2f((u16)(v.z >> 16));
      x[6] += bf2f((u16)(v.w & 0xffff)); x[7] += bf2f((u16)(v.w >> 16));
    }
    if (bias != nullptr) {
      const float4 b0 = *reinterpret_cast<const float4*>(bias + (t << 3));
      const float4 b1 = *reinterpret_cast<const float4*>(bias + (t << 3) + 4);
      x[0] += b0.x; x[1] += b0.y; x[2] += b0.z; x[3] += b0.w;
      x[4] += b1.x; x[5] += b1.y; x[6] += b1.z; x[7] += b1.w;
    }
    const int r = t >> 3, c = (t & 7) << 3;
    float4* d0 = reinterpret_cast<float4*>(&dY[r][c]);
    d0[0] = make_float4(fmaxf(x[0], 0.f), fmaxf(x[1], 0.f), fmaxf(x[2], 0.f), fmaxf(x[3], 0.f));
    d0[1] = make_float4(fmaxf(x[4], 0.f), fmaxf(x[5], 0.f), fmaxf(x[6], 0.f), fmaxf(x[7], 0.f));
  }
  __syncthreads();
  const int p = t >> 3;              // 0..63
  const int j0 = (t << 1) & 15;      // even col
  {
    float a0 = 0.f, a1 = 0.f;
    for (int q = 0; q < 64; ++q) {
      const float d = dY[p][q];
      a0 += d * V[q][j0];
      a1 += d * V[q][j0 + 1];
    }
    P[p][j0] = a0; P[p][j0 + 1] = a1;
    float b0 = 0.f, b1 = 0.f;
    for (int r = 0; r < 64; ++r) {
      const float d = dY[r][p];
      b0 += d * U[r][j0];
      b1 += d * U[r][j0 + 1];
    }
    Q[p][j0] = b0; Q[p][j0 + 1] = b1;
  }
  __syncthreads();
  {
    const int half = t & 1, i = t >> 5, j = (t >> 1) & 15;
    float a = 0.f;
    const int r0 = half << 5;
    for (int r = r0; r < r0 + 32; ++r) a += U[r][i] * P[r][j];
    RS[t] = a;
  }
  __syncthreads();
  if (t < 256) dSs[t >> 4][t & 15] = RS[t << 1] + RS[(t << 1) + 1];
  __syncthreads();
  for (int i = t; i < 1024; i += 512) {
    const int r = i >> 4, c = i & 15;
    const float sc = sinv[c];
    P[r][c] *= sc;
    Q[r][c] *= sc;
  }
  __syncthreads();

  stiefel_update512(U, P, F, T1, G1, G2, M1, RS, t, u_g, ub);
  stiefel_update512(V, Q, F, T1, G1, G2, M1, RS, t, v_g, ub);

  if (t < 256) {
    const int i = t >> 4, j = t & 15;
    const float ns = S[i][j] + 1e-3f * dSs[i][j];
    S[i][j] = ns;
    s_g[((size_t)b << 8) + t] = ns;
  }
  __syncthreads();
  {
    float a0 = 0.f, a1 = 0.f;
    for (int k = 0; k < 16; ++k) {
      const float uk = U[p][k];
      a0 += uk * S[k][j0];
      a1 += uk * S[k][j0 + 1];
    }
    P[p][j0] = a0; P[p][j0 + 1] = a1;
  }
  __syncthreads();
  {
    const int q0 = (t & 7) << 3;
    float res[8];
#pragma unroll
    for (int e = 0; e < 8; ++e) res[e] = 0.f;
    for (int i = 0; i < 16; ++i) {
      const float pi = P[p][i];
#pragma unroll
      for (int e = 0; e < 8; ++e) res[e] += pi * V[q0 + e][i];
    }
    const size_t ko = ((size_t)b << 12) + (p << 6) + q0;
    float4* xo = reinterpret_cast<float4*>(Xf + ko);
    const float4 r0 = make_float4(res[0], res[1], res[2], res[3]);
    const float4 r1 = make_float4(res[4], res[5], res[6], res[7]);
    xo[0] = r0; xo[1] = r1;
    uint4 pk;
    pk.x = pack2bf(res[0], res[1]); pk.y = pack2bf(res[2], res[3]);
    pk.z = pack2bf(res[4], res[5]); pk.w = pack2bf(res[6], res[7]);
    *reinterpret_cast<uint4*>(Xfb + ko) = pk;
    float4* op = reinterpret_cast<float4*>(outL + (size_t)layer * PLANE + ko);
    op[0] = r0; op[1] = r1;
  }
}

// ---------------------------------------------------------------------------
// Pack: outT[b,k,9] <- outL[9][b,k] via LDS, coalesced both sides.
// ---------------------------------------------------------------------------
__global__ __launch_bounds__(256) void pack_kernel(
    const float* __restrict__ outL, float* __restrict__ outT)
{
  const int t = threadIdx.x;
  const int base = blockIdx.x << 8;           // 256 (b,k) pairs per block
  __shared__ float buf[256 * 9];
#pragma unroll
  for (int l = 0; l < 9; ++l)
    buf[t * 9 + l] = outL[(size_t)l * PLANE + base + t];
  __syncthreads();
  const float4* b4 = reinterpret_cast<const float4*>(buf);
  float4* o4 = reinterpret_cast<float4*>(outT + (size_t)base * 9);
  for (int i = t; i < 576; i += 256) o4[i] = b4[i];
}

// ---------------------------------------------------------------------------
// Init: unpack u, s, v from X (per-sample stride 3*1024 floats);
// Xf0 = u s v^T (f32 + bf16 copies)
// ---------------------------------------------------------------------------
__global__ __launch_bounds__(256) void init_kernel(
    const float* __restrict__ X, float* __restrict__ u_g, float* __restrict__ v_g,
    float* __restrict__ s_g, float* __restrict__ Xf, u16* __restrict__ Xfb)
{
  const int b = blockIdx.x, t = threadIdx.x;
  __shared__ float U[64][17], V[64][17], S[16][16], P[64][17];
  const float* xb = X + (size_t)b * 3072;   // (3, 1024) per sample
  const size_t ub = (size_t)b << 10;
  {
    const float4 u4 = *reinterpret_cast<const float4*>(xb + (t << 2));
    const int r = t >> 2, c = (t & 3) << 2;
    U[r][c] = u4.x; U[r][c + 1] = u4.y; U[r][c + 2] = u4.z; U[r][c + 3] = u4.w;
    *reinterpret_cast<float4*>(u_g + ub + (t << 2)) = u4;
    const float sv = xb[1024 + t];
    S[t >> 4][t & 15] = sv;
    s_g[((size_t)b << 8) + t] = sv;
    const float4 v4 = *reinterpret_cast<const float4*>(xb + 2048 + (t << 2));
    const int g = t << 2;
    const int iv = g >> 6, q = g & 63;
    V[q][iv] = v4.x; V[q + 1][iv] = v4.y; V[q + 2][iv] = v4.z; V[q + 3][iv] = v4.w;
    v_g[ub + (size_t)q * 16 + iv] = v4.x;
    v_g[ub + (size_t)(q + 1) * 16 + iv] = v4.y;
    v_g[ub + (size_t)(q + 2) * 16 + iv] = v4.z;
    v_g[ub + (size_t)(q + 3) * 16 + iv] = v4.w;
  }
  __syncthreads();
  const int p4 = t >> 2, e4 = (t & 3) << 2;
#pragma unroll
  for (int e = 0; e < 4; ++e) {
    float a = 0.f;
    for (int i = 0; i < 16; ++i) a += U[p4][i] * S[i][e4 + e];
    P[p4][e4 + e] = a;
  }
  __syncthreads();
  {
    const int q0 = (t & 3) << 4;
    float res[16];
#pragma unroll
    for (int qq = 0; qq < 16; ++qq) {
      float a = 0.f;
      for (int i = 0; i < 16; ++i) a += P[p4][i] * V[q0 + qq][i];
      res[qq] = a;
    }
    const size_t ko = ((size_t)b << 12) + (p4 << 6) + q0;
    float4* xo = reinterpret_cast<float4*>(Xf + ko);
    xo[0] = make_float4(res[0], res[1], res[2], res[3]);
    xo[1] = make_float4(res[4], res[5], res[6], res[7]);
    xo[2] = make_float4(res[8], res[9], res[10], res[11]);
    xo[3] = make_float4(res[12], res[13], res[14], res[15]);
    uint4 pk0, pk1;
    pk0.x = pack2bf(res[0], res[1]);   pk0.y = pack2bf(res[2], res[3]);
    pk0.z = pack2bf(res[4], res[5]);   pk0.w = pack2bf(res[6], res[7]);
    pk1.x = pack2bf(res[8], res[9]);   pk1.y = pack2bf(res[10], res[11]);
    pk1.z = pack2bf(res[12], res[13]); pk1.w = pack2bf(res[14], res[15]);
    *reinterpret_cast<uint4*>(Xfb + ko) = pk0;
    *reinterpret_cast<uint4*>(Xfb + ko + 8) = pk1;
  }
}

// ---------------------------------------------------------------------------
// Classifier: logits = Xf @ Wc^T + bc ; softmax.  256 threads/block.
// ---------------------------------------------------------------------------
__global__ __launch_bounds__(256) void classifier_kernel(
    const float* __restrict__ Xf, const float* __restrict__ Wc,
    const float* __restrict__ bc, float* __restrict__ pred, float* __restrict__ cls)
{
  const int b = blockIdx.x, t = threadIdx.x;
  const int lane = t & 63, w = t >> 6;
  __shared__ float red[4][10];
  float acc[10];
#pragma unroll
  for (int c = 0; c < 10; ++c) acc[c] = 0.f;
  const float* xr = Xf + ((size_t)b << 12);
  for (int k = t; k < 4096; k += 256) {
    const float x = xr[k];
#pragma unroll
    for (int c = 0; c < 10; ++c) acc[c] += x * Wc[c * 4096 + k];
  }
#pragma unroll
  for (int c = 0; c < 10; ++c)
    for (int off = 32; off; off >>= 1) acc[c] += __shfl_xor(acc[c], off);
  if (lane == 0)
#pragma unroll
    for (int c = 0; c < 10; ++c) red[w][c] = acc[c];
  __syncthreads();
  if (t == 0) {
    float lg[10], ex[10];
    float m = -1e30f;
#pragma unroll
    for (int c = 0; c < 10; ++c) {
      lg[c] = red[0][c] + red[1][c] + red[2][c] + red[3][c] + bc[c];
      m = fmaxf(m, lg[c]);
    }
    float s = 0.f;
#pragma unroll
    for (int c = 0; c < 10; ++c) { ex[c] = expf(lg[c] - m); s += ex[c]; }
    const float inv = 1.f / s;
#pragma unroll
    for (int c = 0; c < 10; ++c) {
      cls[b * 10 + c] = lg[c];
      pred[b * 10 + c] = ex[c] * inv;
    }
  }
}

extern "C" void kernel_launch(void* const* d_in, const int* in_sizes, int n_in,
                              void* d_out, int out_size, void* d_ws, size_t ws_size,
                              hipStream_t stream) {
  (void)in_sizes; (void)n_in; (void)out_size; (void)ws_size;
  const float* X  = (const float*)d_in[0];
  const float* W0 = (const float*)d_in[1];
  const float* W  = (const float*)d_in[2];
  const float* bb = (const float*)d_in[3];
  const float* Wc = (const float*)d_in[4];
  const float* bc = (const float*)d_in[5];

  float* out_pred  = (float*)d_out;
  float* out_cls   = out_pred + 2560;
  float* out_trans = out_pred + 5120;

  char* ws = (char*)d_ws;
  float* Xf   = (float*)(ws);                      // 4 MB
  u16*   part = (u16*)  (ws + (4ull << 20));       // 16 MB (8 bf16 split-K planes)
  float* u_g  = (float*)(ws + (20ull << 20));      // 1 MB
  float* v_g  = (float*)(ws + (21ull << 20));      // 1 MB
  float* s_g  = (float*)(ws + (22ull << 20));      // 256 KB
  u16*   Xfb  = (u16*)  (ws + (23ull << 20));      // 2 MB
  float* outL = (float*)(ws + (25ull << 20));      // 36 MB (9 layer planes)

  init_kernel<<<NB, 256, 0, stream>>>(X, u_g, v_g, s_g, Xf, Xfb);
  for (int i = 0; i <= 8; ++i) {
    const float* Wl = (i == 0) ? W0 : W + (size_t)(i - 1) * DD * DD;
    gemm_kernel<<<dim3(64, SPLIT_K), 512, 0, stream>>>(Xfb, Wl, part);
    update_kernel<<<NB, 512, 0, stream>>>(
        part, (i == 0) ? nullptr : (bb + (size_t)(i - 1) * DD),
        u_g, v_g, s_g, Xf, Xfb, outL, i);
  }
  pack_kernel<<<4096, 256, 0, stream>>>(outL, out_trans);
  classifier_kernel<<<NB, 256, 0, stream>>>(Xf, Wc, bc, out_pred, out_cls);
}

// Round 8
// 436.451 us; speedup vs baseline: 2.7177x; 1.0060x over previous
//
#include <hip/hip_runtime.h>
#include <hip/hip_cooperative_groups.h>
#include <math.h>

namespace cg = cooperative_groups;

typedef unsigned short u16;
typedef unsigned int u32;
using bf16x8 = __attribute__((ext_vector_type(8))) short;
using f32x4  = __attribute__((ext_vector_type(4))) float;

#define DD 4096
#define NB 256            // batch
#define SPLIT_K 8
#define PSTRIDE (NB * DD) // elements per partial plane
#define PLANE (NB * DD)   // floats per transform layer plane

__device__ __forceinline__ u16 f2bf(float f) {
  unsigned int u = __float_as_uint(f);
  u += 0x7fffu + ((u >> 16) & 1u);   // RNE
  return (u16)(u >> 16);
}
__device__ __forceinline__ float bf2f(u16 h) {
  return __uint_as_float((u32)h << 16);
}
__device__ __forceinline__ unsigned int pack2bf(float a, float b) {
  return (unsigned int)f2bf(a) | ((unsigned int)f2bf(b) << 16);
}
__device__ __forceinline__ void async_cp16(const u16* g, u16* l) {
  __builtin_amdgcn_global_load_lds(
      (const __attribute__((address_space(1))) unsigned int*)g,
      (__attribute__((address_space(3))) unsigned int*)l, 16, 0, 0);
}

// --------------------------- shared-memory layouts ---------------------------
struct GemmSmem {                    // 40 KB (single-buffered, R6-proven)
  u16 As[256 * 64];
  u16 Bs[64 * 64];
};
struct UpdSmem {                     // 35.1 KB (dY overlaid with stiefel temps)
  float U[64][17], V[64][17], P[64][17], Q[64][17];
  float S[16][16];
  float sinv[16];
  union {
    float dY[64][68];                // live: partial-sum .. P/Q formation
    struct {                         // live: after P/Q formed
      float F[64][17];
      float T1[16][17], G1[16][17], G2[16][17], M1[16][17], dSs[16][17];
      float RS[512];
    };
  };
};
struct PackSmem { float buf[512 * 9]; };   // 18 KB
struct ClsSmem  { float red[8][10]; };

// ------------------------------- GEMM phase ---------------------------------
// part[kz] = Xf(bf16) @ W^T over K-chunk kz (K=512), output bf16.
// tile: nt = tile&63 (64 output cols), kz = tile>>6.  Tile 256x64, BK=64,
// simple sync-per-iter loop; 2 WGs/CU provide the latency overlap.
__device__ __forceinline__ void gemm_phase(
    GemmSmem& sm, const u16* __restrict__ A, const float* __restrict__ W,
    u16* __restrict__ part, int tile, int t)
{
  const int nt = tile & 63, kz = tile >> 6;
  const int w = t >> 6, l = t & 63;
  const int colg0 = nt << 6;
  const int k0 = kz << 9;                      // K-chunk of 512

  f32x4 acc[4][2];
#pragma unroll
  for (int mi = 0; mi < 4; ++mi)
#pragma unroll
    for (int nj = 0; nj < 2; ++nj)
      acc[mi][nj] = (f32x4){0.f, 0.f, 0.f, 0.f};

  const int wm = w & 3, wn = w >> 2;      // wave tile: rows 64*wm, cols 32*wn
  const int lr = l & 15, lg = l >> 4;
  const int arow_l = (w << 3) + (l >> 3); // A stage row (per rep +64)
  const int acl = l & 7;                  // linear chunk within row
  const int bn_l = t >> 3;                // B stage: W row (output col)
  const int bcc = t & 7;                  // B stage: chunk

  for (int tt = 0; tt < 8; ++tt) {
    const int kk = k0 + (tt << 6);
    __syncthreads();                      // LDS safe to overwrite
#pragma unroll
    for (int r = 0; r < 4; ++r) {
      const int row = (r << 6) + arow_l;
      const int cs = acl ^ (row & 7);
      async_cp16(A + ((size_t)row << 12) + kk + (cs << 3),
                 &sm.As[(r << 12) + (w << 9)]);
    }
    {
      const float* wsrc = W + ((size_t)(colg0 + bn_l) << 12) + kk + (bcc << 3);
      const float4 f0 = *reinterpret_cast<const float4*>(wsrc);
      const float4 f1 = *reinterpret_cast<const float4*>(wsrc + 4);
      uint4 pk;
      pk.x = pack2bf(f0.x, f0.y);
      pk.y = pack2bf(f0.z, f0.w);
      pk.z = pack2bf(f1.x, f1.y);
      pk.w = pack2bf(f1.z, f1.w);
      *reinterpret_cast<uint4*>(&sm.Bs[(bn_l << 6) + ((bcc ^ (bn_l & 7)) << 3)]) = pk;
    }
    __syncthreads();                      // vmcnt(0)+lgkmcnt(0)+barrier
#pragma unroll
    for (int ks = 0; ks < 2; ++ks) {
      const int cg2 = (ks << 2) + lg;
      bf16x8 av[4], bv[2];
#pragma unroll
      for (int mi = 0; mi < 4; ++mi) {
        const int fr = (wm << 6) + (mi << 4) + lr;
        av[mi] = *reinterpret_cast<const bf16x8*>(&sm.As[(fr << 6) + ((cg2 ^ (fr & 7)) << 3)]);
      }
#pragma unroll
      for (int nj = 0; nj < 2; ++nj) {
        const int fc = (wn << 5) + (nj << 4) + lr;
        bv[nj] = *reinterpret_cast<const bf16x8*>(&sm.Bs[(fc << 6) + ((cg2 ^ (fc & 7)) << 3)]);
      }
#pragma unroll
      for (int mi = 0; mi < 4; ++mi)
#pragma unroll
        for (int nj = 0; nj < 2; ++nj)
          acc[mi][nj] = __builtin_amdgcn_mfma_f32_16x16x32_bf16(
              av[mi], bv[nj], acc[mi][nj], 0, 0, 0);
    }
  }

  u16* pout = part + (size_t)kz * PSTRIDE;
#pragma unroll
  for (int mi = 0; mi < 4; ++mi)
#pragma unroll
    for (int nj = 0; nj < 2; ++nj) {
      const int col = colg0 + (wn << 5) + (nj << 4) + lr;
#pragma unroll
      for (int j = 0; j < 4; ++j) {
        const int row = (wm << 6) + (mi << 4) + (lg << 2) + j;
        pout[((size_t)row << 12) + col] = f2bf(acc[mi][nj][j]);
      }
    }
}

// ------------------------- Stiefel update (512 thr) --------------------------
// new_A = A - H^2 * F @ (A^T F) @ (A^T A)   (Cayley collapsed; H^4 ~ 1e-13)
__device__ __forceinline__ void stiefel_update512(
    UpdSmem& m, float (&Am)[64][17], float (&Dm)[64][17],
    int t, float* __restrict__ gout, size_t ub)
{
  const int p = t >> 3;
  const int j0 = (t << 1) & 15;
  {
    const int half = t & 1, i = t >> 5, j = (t >> 1) & 15;
    float a = 0.f;
    const int r0 = half << 5;
    for (int r = r0; r < r0 + 32; ++r) a += Am[r][i] * Dm[r][j];
    m.RS[t] = a;
  }
  __syncthreads();
  if (t < 256) m.T1[t >> 4][t & 15] = m.RS[t << 1] + m.RS[(t << 1) + 1];
  __syncthreads();
  {
    float f0 = Dm[p][j0], f1 = Dm[p][j0 + 1];
    for (int k = 0; k < 16; ++k) {
      const float ak = Am[p][k];
      f0 -= ak * m.T1[k][j0];
      f1 -= ak * m.T1[k][j0 + 1];
    }
    m.F[p][j0] = f0; m.F[p][j0 + 1] = f1;
  }
  __syncthreads();
  if (t < 256) {
    const int i = t >> 4, j = t & 15;
    float g = 0.f;
    for (int r = 0; r < 64; ++r) g += Am[r][i] * m.F[r][j];
    m.G1[i][j] = g;
  } else {
    const int tt = t - 256, i = tt >> 4, j = tt & 15;
    float g = 0.f;
    for (int r = 0; r < 64; ++r) g += Am[r][i] * Am[r][j];
    m.G2[i][j] = g;
  }
  __syncthreads();
  if (t < 256) {
    const int i = t >> 4, j = t & 15;
    float mm = 0.f;
    for (int k = 0; k < 16; ++k) mm += m.G1[i][k] * m.G2[k][j];
    m.M1[i][j] = mm;
  }
  __syncthreads();
  {
    float a0 = 0.f, a1 = 0.f;
    for (int k = 0; k < 16; ++k) {
      const float fk = m.F[p][k];
      a0 += fk * m.M1[k][j0];
      a1 += fk * m.M1[k][j0 + 1];
    }
    const float n0 = Am[p][j0] - 1e-6f * a0;
    const float n1 = Am[p][j0 + 1] - 1e-6f * a1;
    __syncthreads();
    Am[p][j0] = n0; Am[p][j0 + 1] = n1;
    *reinterpret_cast<float2*>(gout + ub + (p << 4) + j0) = make_float2(n0, n1);
  }
  __syncthreads();
}

// Xf = (U @ S) @ V^T ; writes f32 Xf, bf16 Xfb, optional layer plane.
__device__ __forceinline__ void write_xf_tail(
    UpdSmem& m, int t, int b, float* __restrict__ Xf, u16* __restrict__ Xfb,
    float* __restrict__ outL_plane)
{
  const int p = t >> 3;
  const int j0 = (t << 1) & 15;
  {
    float a0 = 0.f, a1 = 0.f;
    for (int k = 0; k < 16; ++k) {
      const float uk = m.U[p][k];
      a0 += uk * m.S[k][j0];
      a1 += uk * m.S[k][j0 + 1];
    }
    m.P[p][j0] = a0; m.P[p][j0 + 1] = a1;
  }
  __syncthreads();
  {
    const int q0 = (t & 7) << 3;
    float res[8];
#pragma unroll
    for (int e = 0; e < 8; ++e) res[e] = 0.f;
    for (int i = 0; i < 16; ++i) {
      const float pi = m.P[p][i];
#pragma unroll
      for (int e = 0; e < 8; ++e) res[e] += pi * m.V[q0 + e][i];
    }
    const size_t ko = ((size_t)b << 12) + (p << 6) + q0;
    float4* xo = reinterpret_cast<float4*>(Xf + ko);
    const float4 r0 = make_float4(res[0], res[1], res[2], res[3]);
    const float4 r1 = make_float4(res[4], res[5], res[6], res[7]);
    xo[0] = r0; xo[1] = r1;
    uint4 pk;
    pk.x = pack2bf(res[0], res[1]); pk.y = pack2bf(res[2], res[3]);
    pk.z = pack2bf(res[4], res[5]); pk.w = pack2bf(res[6], res[7]);
    *reinterpret_cast<uint4*>(Xfb + ko) = pk;
    if (outL_plane != nullptr) {
      float4* op = reinterpret_cast<float4*>(outL_plane + ko);
      op[0] = r0; op[1] = r1;
    }
  }
}

// ------------------------------ update phase --------------------------------
__device__ __forceinline__ void update_phase(
    UpdSmem& m, const u16* __restrict__ part, const float* __restrict__ bias,
    float* __restrict__ u_g, float* __restrict__ v_g, float* __restrict__ s_g,
    float* __restrict__ Xf, u16* __restrict__ Xfb,
    float* __restrict__ outL_plane, int b, int t)
{
  const size_t ub = (size_t)b << 10;
  {
    const float2 u2 = *reinterpret_cast<const float2*>(u_g + ub + (t << 1));
    const float2 v2 = *reinterpret_cast<const float2*>(v_g + ub + (t << 1));
    const int r = t >> 3, c = (t & 7) << 1;
    m.U[r][c] = u2.x; m.U[r][c + 1] = u2.y;
    m.V[r][c] = v2.x; m.V[r][c + 1] = v2.y;
    if (t < 256) m.S[t >> 4][t & 15] = s_g[((size_t)b << 8) + t];
  }
  __syncthreads();
  if (t < 16) m.sinv[t] = 1.0f / m.S[t][t];
  {
    const u16* p0 = part + ((size_t)b << 12) + (t << 3);
    float x[8];
#pragma unroll
    for (int e = 0; e < 8; ++e) x[e] = 0.f;
#pragma unroll
    for (int kzi = 0; kzi < SPLIT_K; ++kzi) {
      const uint4 v = *reinterpret_cast<const uint4*>(p0 + (size_t)kzi * PSTRIDE);
      x[0] += bf2f((u16)(v.x & 0xffff)); x[1] += bf2f((u16)(v.x >> 16));
      x[2] += bf2f((u16)(v.y & 0xffff)); x[3] += bf2f((u16)(v.y >> 16));
      x[4] += bf2f((u16)(v.z & 0xffff)); x[5] += bf2f((u16)(v.z >> 16));
      x[6] += bf2f((u16)(v.w & 0xffff)); x[7] += bf2f((u16)(v.w >> 16));
    }
    if (bias != nullptr) {
      const float4 b0 = *reinterpret_cast<const float4*>(bias + (t << 3));
      const float4 b1 = *reinterpret_cast<const float4*>(bias + (t << 3) + 4);
      x[0] += b0.x; x[1] += b0.y; x[2] += b0.z; x[3] += b0.w;
      x[4] += b1.x; x[5] += b1.y; x[6] += b1.z; x[7] += b1.w;
    }
    const int r = t >> 3, c = (t & 7) << 3;
    float4* d0 = reinterpret_cast<float4*>(&m.dY[r][c]);
    d0[0] = make_float4(fmaxf(x[0], 0.f), fmaxf(x[1], 0.f), fmaxf(x[2], 0.f), fmaxf(x[3], 0.f));
    d0[1] = make_float4(fmaxf(x[4], 0.f), fmaxf(x[5], 0.f), fmaxf(x[6], 0.f), fmaxf(x[7], 0.f));
  }
  __syncthreads();
  const int p = t >> 3;
  const int j0 = (t << 1) & 15;
  {
    float a0 = 0.f, a1 = 0.f;
    for (int q = 0; q < 64; ++q) {
      const float d = m.dY[p][q];
      a0 += d * m.V[q][j0];
      a1 += d * m.V[q][j0 + 1];
    }
    float b0 = 0.f, b1 = 0.f;
    for (int r = 0; r < 64; ++r) {
      const float d = m.dY[r][p];
      b0 += d * m.U[r][j0];
      b1 += d * m.U[r][j0 + 1];
    }
    m.P[p][j0] = a0; m.P[p][j0 + 1] = a1;
    m.Q[p][j0] = b0; m.Q[p][j0 + 1] = b1;
  }
  __syncthreads();           // dY dead from here; union side F/T1/../RS live
  {
    const int half = t & 1, i = t >> 5, j = (t >> 1) & 15;
    float a = 0.f;
    const int r0 = half << 5;
    for (int r = r0; r < r0 + 32; ++r) a += m.U[r][i] * m.P[r][j];
    m.RS[t] = a;
  }
  __syncthreads();
  if (t < 256) m.dSs[t >> 4][t & 15] = m.RS[t << 1] + m.RS[(t << 1) + 1];
  __syncthreads();
  for (int i = t; i < 1024; i += 512) {
    const int r = i >> 4, c = i & 15;
    const float sc = m.sinv[c];
    m.P[r][c] *= sc;
    m.Q[r][c] *= sc;
  }
  __syncthreads();

  stiefel_update512(m, m.U, m.P, t, u_g, ub);
  stiefel_update512(m, m.V, m.Q, t, v_g, ub);

  if (t < 256) {
    const int i = t >> 4, j = t & 15;
    const float ns = m.S[i][j] + 1e-3f * m.dSs[i][j];
    m.S[i][j] = ns;
    s_g[((size_t)b << 8) + t] = ns;
  }
  __syncthreads();
  write_xf_tail(m, t, b, Xf, Xfb, outL_plane);
}

// ------------------------------- init phase ---------------------------------
__device__ __forceinline__ void init_phase(
    UpdSmem& m, const float* __restrict__ X,
    float* __restrict__ u_g, float* __restrict__ v_g, float* __restrict__ s_g,
    float* __restrict__ Xf, u16* __restrict__ Xfb, int b, int t)
{
  const float* xb = X + (size_t)b * 3072;
  const size_t ub = (size_t)b << 10;
  {
    const float2 u2 = *reinterpret_cast<const float2*>(xb + (t << 1));
    const int r = t >> 3, c = (t & 7) << 1;
    m.U[r][c] = u2.x; m.U[r][c + 1] = u2.y;
    *reinterpret_cast<float2*>(u_g + ub + (t << 1)) = u2;
    if (t < 256) {
      const float sv = xb[1024 + t];
      m.S[t >> 4][t & 15] = sv;
      s_g[((size_t)b << 8) + t] = sv;
    }
    const float2 v2 = *reinterpret_cast<const float2*>(xb + 2048 + (t << 1));
    const int g2 = t << 1;
    const int iv = g2 >> 6, q = g2 & 63;
    m.V[q][iv] = v2.x; m.V[q + 1][iv] = v2.y;
    v_g[ub + (size_t)q * 16 + iv] = v2.x;
    v_g[ub + (size_t)(q + 1) * 16 + iv] = v2.y;
  }
  __syncthreads();
  write_xf_tail(m, t, b, Xf, Xfb, nullptr);
}

// ------------------------------- mega kernel --------------------------------
__global__ __launch_bounds__(512, 4) void mega_kernel(
    const float* __restrict__ X, const float* __restrict__ W0,
    const float* __restrict__ W, const float* __restrict__ bb,
    const float* __restrict__ Wc, const float* __restrict__ bc,
    float* __restrict__ pred, float* __restrict__ cls, float* __restrict__ outT,
    float* __restrict__ Xf, u16* __restrict__ part,
    float* __restrict__ u_g, float* __restrict__ v_g, float* __restrict__ s_g,
    u16* __restrict__ Xfb, float* __restrict__ outL)
{
  cg::grid_group grid = cg::this_grid();
  __shared__ __align__(16) char smem_raw[sizeof(GemmSmem)];   // 40 KB max phase
  GemmSmem& gs = *reinterpret_cast<GemmSmem*>(smem_raw);
  UpdSmem&  us = *reinterpret_cast<UpdSmem*>(smem_raw);
  PackSmem& ps = *reinterpret_cast<PackSmem*>(smem_raw);
  ClsSmem&  cs = *reinterpret_cast<ClsSmem*>(smem_raw);

  const int g = blockIdx.x, t = threadIdx.x;
  const int nwg = gridDim.x;

  for (int b = g; b < NB; b += nwg)
    init_phase(us, X, u_g, v_g, s_g, Xf, Xfb, b, t);
  grid.sync();

  for (int layer = 0; layer <= 8; ++layer) {
    const float* Wl = (layer == 0) ? W0 : W + (size_t)(layer - 1) * DD * DD;
    for (int tile = g; tile < 64 * SPLIT_K; tile += nwg)
      gemm_phase(gs, Xfb, Wl, part, tile, t);
    grid.sync();
    for (int b = g; b < NB; b += nwg)
      update_phase(us, part, (layer == 0) ? nullptr : (bb + (size_t)(layer - 1) * DD),
                   u_g, v_g, s_g, Xf, Xfb,
                   outL + (size_t)layer * PLANE, b, t);
    grid.sync();
  }

  // ---- classifier ----
  for (int b = g; b < NB; b += nwg) {
    const int lane = t & 63, w = t >> 6;
    float acc[10];
#pragma unroll
    for (int c = 0; c < 10; ++c) acc[c] = 0.f;
    const float* xr = Xf + ((size_t)b << 12);
    for (int k = t; k < 4096; k += 512) {
      const float x = xr[k];
#pragma unroll
      for (int c = 0; c < 10; ++c) acc[c] += x * Wc[c * 4096 + k];
    }
#pragma unroll
    for (int c = 0; c < 10; ++c)
      for (int off = 32; off; off >>= 1) acc[c] += __shfl_xor(acc[c], off);
    if (lane == 0)
#pragma unroll
      for (int c = 0; c < 10; ++c) cs.red[w][c] = acc[c];
    __syncthreads();
    if (t == 0) {
      float lg[10], ex[10];
      float mx = -1e30f;
#pragma unroll
      for (int c = 0; c < 10; ++c) {
        float s8 = 0.f;
#pragma unroll
        for (int ww = 0; ww < 8; ++ww) s8 += cs.red[ww][c];
        lg[c] = s8 + bc[c];
        mx = fmaxf(mx, lg[c]);
      }
      float s = 0.f;
#pragma unroll
      for (int c = 0; c < 10; ++c) { ex[c] = expf(lg[c] - mx); s += ex[c]; }
      const float inv = 1.f / s;
#pragma unroll
      for (int c = 0; c < 10; ++c) {
        cls[b * 10 + c] = lg[c];
        pred[b * 10 + c] = ex[c] * inv;
      }
    }
    __syncthreads();
  }

  // ---- pack: outT[b,k,9] <- outL[9][b,k]; 2048 chunks of 512 pairs ----
  for (int ch = g; ch < 2048; ch += nwg) {
    const int base = ch << 9;
#pragma unroll
    for (int l = 0; l < 9; ++l)
      ps.buf[t * 9 + l] = outL[(size_t)l * PLANE + base + t];
    __syncthreads();
    const float4* b4 = reinterpret_cast<const float4*>(ps.buf);
    float4* o4 = reinterpret_cast<float4*>(outT + (size_t)base * 9);
    for (int i = t; i < 1152; i += 512) o4[i] = b4[i];
    __syncthreads();
  }
}

// --------------------------- standalone kernels ------------------------------
__global__ __launch_bounds__(512, 4) void gemm_kernel(
    const u16* __restrict__ A, const float* __restrict__ W,
    u16* __restrict__ part)
{
  __shared__ __align__(16) GemmSmem sm;
  gemm_phase(sm, A, W, part, (int)(blockIdx.x + (blockIdx.y << 6)), (int)threadIdx.x);
}

__global__ __launch_bounds__(512) void update_kernel(
    const u16* __restrict__ part, const float* __restrict__ bias,
    float* __restrict__ u_g, float* __restrict__ v_g, float* __restrict__ s_g,
    float* __restrict__ Xf, u16* __restrict__ Xfb,
    float* __restrict__ outL, int layer)
{
  __shared__ __align__(16) UpdSmem m;
  update_phase(m, part, bias, u_g, v_g, s_g, Xf, Xfb,
               outL + (size_t)layer * PLANE, (int)blockIdx.x, (int)threadIdx.x);
}

__global__ __launch_bounds__(512) void init_kernel(
    const float* __restrict__ X, float* __restrict__ u_g, float* __restrict__ v_g,
    float* __restrict__ s_g, float* __restrict__ Xf, u16* __restrict__ Xfb)
{
  __shared__ __align__(16) UpdSmem m;
  init_phase(m, X, u_g, v_g, s_g, Xf, Xfb, (int)blockIdx.x, (int)threadIdx.x);
}

__global__ __launch_bounds__(256) void pack_kernel(
    const float* __restrict__ outL, float* __restrict__ outT)
{
  const int t = threadIdx.x;
  const int base = blockIdx.x << 8;
  __shared__ float buf[256 * 9];
#pragma unroll
  for (int l = 0; l < 9; ++l)
    buf[t * 9 + l] = outL[(size_t)l * PLANE + base + t];
  __syncthreads();
  const float4* b4 = reinterpret_cast<const float4*>(buf);
  float4* o4 = reinterpret_cast<float4*>(outT + (size_t)base * 9);
  for (int i = t; i < 576; i += 256) o4[i] = b4[i];
}

__global__ __launch_bounds__(256) void classifier_kernel(
    const float* __restrict__ Xf, const float* __restrict__ Wc,
    const float* __restrict__ bc, float* __restrict__ pred, float* __restrict__ cls)
{
  const int b = blockIdx.x, t = threadIdx.x;
  const int lane = t & 63, w = t >> 6;
  __shared__ float red[4][10];
  float acc[10];
#pragma unroll
  for (int c = 0; c < 10; ++c) acc[c] = 0.f;
  const float* xr = Xf + ((size_t)b << 12);
  for (int k = t; k < 4096; k += 256) {
    const float x = xr[k];
#pragma unroll
    for (int c = 0; c < 10; ++c) acc[c] += x * Wc[c * 4096 + k];
  }
#pragma unroll
  for (int c = 0; c < 10; ++c)
    for (int off = 32; off; off >>= 1) acc[c] += __shfl_xor(acc[c], off);
  if (lane == 0)
#pragma unroll
    for (int c = 0; c < 10; ++c) red[w][c] = acc[c];
  __syncthreads();
  if (t == 0) {
    float lg[10], ex[10];
    float m = -1e30f;
#pragma unroll
    for (int c = 0; c < 10; ++c) {
      lg[c] = red[0][c] + red[1][c] + red[2][c] + red[3][c] + bc[c];
      m = fmaxf(m, lg[c]);
    }
    float s = 0.f;
#pragma unroll
    for (int c = 0; c < 10; ++c) { ex[c] = expf(lg[c] - m); s += ex[c]; }
    const float inv = 1.f / s;
#pragma unroll
    for (int c = 0; c < 10; ++c) {
      cls[b * 10 + c] = lg[c];
      pred[b * 10 + c] = ex[c] * inv;
    }
  }
}

extern "C" void kernel_launch(void* const* d_in, const int* in_sizes, int n_in,
                              void* d_out, int out_size, void* d_ws, size_t ws_size,
                              hipStream_t stream) {
  (void)in_sizes; (void)n_in; (void)out_size; (void)ws_size;
  const float* X  = (const float*)d_in[0];
  const float* W0 = (const float*)d_in[1];
  const float* W  = (const float*)d_in[2];
  const float* bb = (const float*)d_in[3];
  const float* Wc = (const float*)d_in[4];
  const float* bc = (const float*)d_in[5];

  float* out_pred  = (float*)d_out;
  float* out_cls   = out_pred + 2560;
  float* out_trans = out_pred + 5120;

  char* ws = (char*)d_ws;
  float* Xf   = (float*)(ws);                      // 4 MB
  u16*   part = (u16*)  (ws + (4ull << 20));       // 16 MB (8 bf16 split-K planes)
  float* u_g  = (float*)(ws + (20ull << 20));      // 1 MB
  float* v_g  = (float*)(ws + (21ull << 20));      // 1 MB
  float* s_g  = (float*)(ws + (22ull << 20));      // 256 KB
  u16*   Xfb  = (u16*)  (ws + (23ull << 20));      // 2 MB
  float* outL = (float*)(ws + (25ull << 20));      // 36 MB (9 layer planes)

  // Decide path from a host-side occupancy query (deterministic, capture-safe).
  int occ = 0;
  (void)hipOccupancyMaxActiveBlocksPerMultiprocessor(
      &occ, (const void*)mega_kernel, 512, 0);

  bool done = false;
  if (occ >= 2) {
    void* kargs[] = {
      (void*)&X, (void*)&W0, (void*)&W, (void*)&bb, (void*)&Wc, (void*)&bc,
      (void*)&out_pred, (void*)&out_cls, (void*)&out_trans,
      (void*)&Xf, (void*)&part, (void*)&u_g, (void*)&v_g, (void*)&s_g,
      (void*)&Xfb, (void*)&outL
    };
    hipError_t e = hipLaunchCooperativeKernel((const void*)mega_kernel,
                                              dim3(512), dim3(512),
                                              kargs, 0, stream);
    if (e == hipSuccess) done = true;
    else (void)hipGetLastError();          // clear sticky error, take fallback
  }

  if (!done) {
    init_kernel<<<NB, 512, 0, stream>>>(X, u_g, v_g, s_g, Xf, Xfb);
    for (int i = 0; i <= 8; ++i) {
      const float* Wl = (i == 0) ? W0 : W + (size_t)(i - 1) * DD * DD;
      gemm_kernel<<<dim3(64, SPLIT_K), 512, 0, stream>>>(Xfb, Wl, part);
      update_kernel<<<NB, 512, 0, stream>>>(
          part, (i == 0) ? nullptr : (bb + (size_t)(i - 1) * DD),
          u_g, v_g, s_g, Xf, Xfb, outL, i);
    }
    pack_kernel<<<4096, 256, 0, stream>>>(outL, out_trans);
    classifier_kernel<<<NB, 256, 0, stream>>>(Xf, Wc, bc, out_pred, out_cls);
  }
}